// Round 7
// baseline (9003.881 us; speedup 1.0000x reference)
//
#include <hip/hip_runtime.h>
#include <stdint.h>
#include <stddef.h>

// SimpleRNN: B=64, T=512, D_IN=256, H=1024, D_OUT=256 (all fp32 in/out)
//
//  A) xproj:  xp = inputs @ W_in + b_h, bf16, pre-swizzled in MFMA C-frag
//     order so the scan adds it with one 8B load.
//  B) scan:   persistent, 4 groups(16 batch rows) x 16 WGs.  WG j of group
//     g owns h cols [64j,64j+64); W_h[:,cols] register resident as bf16
//     B-fragments.  Exchange protocol (round 7):
//       - grid 128; group g = blocks with blk%8==g (g<4).  If the HW's
//         round-robin block->XCD mapping holds, all 16 WGs of a group land
//         on ONE XCD and share its L2 (RT ~200-300cy vs LLC ~1400cy).
//       - runtime XCC_ID check (s_getreg HW_REG_XCC_ID, m09) picks per
//         group: FAST (plain stores -> shared L2; sc0 polls bypass L1) or
//         FALLBACK (R3's merged detect+fetch via LLC relaxed atomics).
//       - producers ALWAYS also store via LLC atomics (backup); the sc0
//         poll is bounded and falls back to the LLC fetch -> correct under
//         every possible block->XCD mapping.
//       - data-as-flag: d_ws poisoned 0xAA by the harness; a fragment is
//         ready when none of its qwords equal the poison pattern.
//  C) outproj: out = H @ W_out + b_o, A-frags from packed h buffer
//     (kernel-boundary L2 writeback makes fast-path stores visible).

#define TT 512
#define HH 1024

typedef __attribute__((ext_vector_type(8))) short short8;
typedef __attribute__((ext_vector_type(4))) short s16x4;
typedef __attribute__((ext_vector_type(4))) float f32x4;
typedef __attribute__((ext_vector_type(4))) int iv4;
typedef unsigned long long u64;

#define POISON 0xAAAAAAAAAAAAAAAAull

__device__ inline short f2bf(float f) {
  uint32_t u = __builtin_bit_cast(uint32_t, f);
  u += 0x7fffu + ((u >> 16) & 1u);
  return (short)(u >> 16);
}

__device__ inline float bf2f(short s) {
  uint32_t u = ((uint32_t)(uint16_t)s) << 16;
  return __builtin_bit_cast(float, u);
}

__device__ inline float fast_tanh(float x) {
  float ax = fabsf(x);
  float e = __expf(-2.f * ax);
  float r = (1.f - e) * __builtin_amdgcn_rcpf(1.f + e);
  return copysignf(r, x);
}

// LLC-atomic fetch of 8 fragments (16 qwords), retry until poison-free.
__device__ inline void atomic_fetch_frags(const u64* hq, size_t base, short8* af) {
  u64 q[16];
  int bad;
  do {
#pragma unroll
    for (int f = 0; f < 8; ++f) {
      q[2 * f]     = __hip_atomic_load(hq + base + (size_t)f * 128,
                                       __ATOMIC_RELAXED, __HIP_MEMORY_SCOPE_AGENT);
      q[2 * f + 1] = __hip_atomic_load(hq + base + (size_t)f * 128 + 1,
                                       __ATOMIC_RELAXED, __HIP_MEMORY_SCOPE_AGENT);
    }
    int mybad = 0;
#pragma unroll
    for (int i = 0; i < 16; ++i) mybad |= (q[i] == POISON);
    bad = __any(mybad);
  } while (bad);
#pragma unroll
  for (int f = 0; f < 8; ++f) {
    union { u64 qq[2]; short8 s; } u;
    u.qq[0] = q[2 * f];
    u.qq[1] = q[2 * f + 1];
    af[f] = u.s;
  }
}

// ---------------------------------------------------------------------------
// Phase A: xp[(t*4+g)*64 + ntile][lane][4] = inputs @ W_in + b_h  (bf16)
// ---------------------------------------------------------------------------
__global__ __launch_bounds__(256, 1) void xproj_kernel(
    const float* __restrict__ inp, const float* __restrict__ w_in,
    const float* __restrict__ h_b, short* __restrict__ xp) {
  const int blk = blockIdx.x;
  const int c = blk & 3, s = blk >> 2;
  const int tid = threadIdx.x;
  const int wv = tid >> 6, l = tid & 63, lr = l & 15, lq = l >> 4;

  __shared__ short ldsA[16 * 264];

  short8 wf[8][4];
#pragma unroll
  for (int kt = 0; kt < 8; ++kt)
#pragma unroll
    for (int nt = 0; nt < 4; ++nt) {
      int col = c * 256 + (wv * 4 + nt) * 16 + lr;
      int k0 = kt * 32 + lq * 8;
      short8 v;
#pragma unroll
      for (int e = 0; e < 8; ++e) v[e] = f2bf(w_in[(size_t)(k0 + e) * HH + col]);
      wf[kt][nt] = v;
    }
  float bias[4];
#pragma unroll
  for (int nt = 0; nt < 4; ++nt) bias[nt] = h_b[c * 256 + (wv * 4 + nt) * 16 + lr];

  for (int it = 0; it < 8; ++it) {
    int m = s + 256 * it;
    int t = m >> 2, g = m & 3;
    {
      int row = tid >> 4, cb = (tid & 15) * 16;
      const float* src = inp + ((size_t)(g * 16 + row) * TT + t) * 256 + cb;
      f32x4 v0 = *(const f32x4*)(src);
      f32x4 v1 = *(const f32x4*)(src + 4);
      f32x4 v2 = *(const f32x4*)(src + 8);
      f32x4 v3 = *(const f32x4*)(src + 12);
      short8 sa, sb;
      sa[0]=f2bf(v0[0]); sa[1]=f2bf(v0[1]); sa[2]=f2bf(v0[2]); sa[3]=f2bf(v0[3]);
      sa[4]=f2bf(v1[0]); sa[5]=f2bf(v1[1]); sa[6]=f2bf(v1[2]); sa[7]=f2bf(v1[3]);
      sb[0]=f2bf(v2[0]); sb[1]=f2bf(v2[1]); sb[2]=f2bf(v2[2]); sb[3]=f2bf(v2[3]);
      sb[4]=f2bf(v3[0]); sb[5]=f2bf(v3[1]); sb[6]=f2bf(v3[2]); sb[7]=f2bf(v3[3]);
      *(short8*)&ldsA[row * 264 + cb] = sa;
      *(short8*)&ldsA[row * 264 + cb + 8] = sb;
    }
    __syncthreads();

    f32x4 acc[4];
#pragma unroll
    for (int nt = 0; nt < 4; ++nt) acc[nt] = (f32x4){0.f, 0.f, 0.f, 0.f};
#pragma unroll
    for (int kt = 0; kt < 8; ++kt) {
      short8 a = *(const short8*)&ldsA[lr * 264 + kt * 32 + lq * 8];
#pragma unroll
      for (int nt = 0; nt < 4; ++nt)
        acc[nt] = __builtin_amdgcn_mfma_f32_16x16x32_bf16(a, wf[kt][nt], acc[nt], 0, 0, 0);
    }
#pragma unroll
    for (int nt = 0; nt < 4; ++nt) {
      s16x4 o;
#pragma unroll
      for (int i2 = 0; i2 < 4; ++i2) o[i2] = f2bf(acc[nt][i2] + bias[nt]);
      *(s16x4*)(xp + ((size_t)(t * 4 + g) * 64 + c * 16 + wv * 4 + nt) * 256 + l * 4) = o;
    }
    __syncthreads();
  }
}

// ---------------------------------------------------------------------------
// Phase B: persistent scan.  grid 128: r=blk&7, j=blk>>3; live iff r<4
// (g=r).  hbuf frag fi=(t*4+g)*32+kt: 64 lanes x 16B, A-frag layout.
// ---------------------------------------------------------------------------
__global__ __launch_bounds__(256, 1) void scan_kernel(
    const short* __restrict__ xp, const float* __restrict__ w_h,
    short* __restrict__ hbuf, int* __restrict__ xcmap) {
  const int blk = blockIdx.x;
  const int r = blk & 7, j = blk >> 3;
  if (r >= 4) return;
  const int g = r;
  const int tid = threadIdx.x;
  const int wv = tid >> 6, l = tid & 63, lr = l & 15, lq = l >> 4;
  const int ntg = j * 4 + wv;

  __shared__ f32x4 red[2][4][4][64];  // [t&1][src wave][n-tile][lane]
  __shared__ short ldsw[4][16 * 24];  // per-wave C->A transpose tile

  // --- XCD co-residency check (once) -------------------------------------
  int myxcc = __builtin_amdgcn_s_getreg((31 << 11) | 20) & 0xf;  // HW_REG_XCC_ID
  if (tid == 0)
    __hip_atomic_store(xcmap + g * 16 + j, myxcc,
                       __ATOMIC_RELAXED, __HIP_MEMORY_SCOPE_AGENT);
  int e;
  do {
    e = __hip_atomic_load(xcmap + g * 16 + (l & 15),
                          __ATOMIC_RELAXED, __HIP_MEMORY_SCOPE_AGENT);
  } while (__any(e < 0 || e > 15));
  const int e0 = __shfl(e, 0);
  const bool fast = !__any(e != e0);   // wave-uniform, same for all waves

  // --- W_h B-fragments, register resident --------------------------------
  short8 wf[8][4];
#pragma unroll
  for (int f = 0; f < 8; ++f)
#pragma unroll
    for (int nt = 0; nt < 4; ++nt) {
      int n = j * 64 + nt * 16 + lr;
      int k0 = wv * 256 + f * 32 + lq * 8;
      short8 v;
#pragma unroll
      for (int e2 = 0; e2 < 8; ++e2) v[e2] = f2bf(w_h[(size_t)(k0 + e2) * HH + n]);
      wf[f][nt] = v;
    }

  const u64* hq = (const u64*)hbuf;

  for (int t = 0; t < TT; ++t) {
    s16x4 xps = *(const s16x4*)(xp + ((size_t)(t * 4 + g) * 64 + ntg) * 256 + l * 4);

    f32x4 acc[4];
#pragma unroll
    for (int nt = 0; nt < 4; ++nt) acc[nt] = (f32x4){0.f, 0.f, 0.f, 0.f};

    if (t > 0) {
      short8 af[8];
      const size_t fi0 = ((size_t)(t - 1) * 4 + g) * 32 + wv * 8;
      if (fast) {
        // sc0 loads: bypass L1, served by the shared XCD L2 where the
        // producers' plain stores landed.  Bounded retry; LLC backup
        // stores guarantee the atomic path succeeds if this trips.
        uint64_t p0 = (uint64_t)((const char*)hbuf + fi0 * 1024 + (size_t)l * 16);
        uint64_t p1 = p0 + 4096;
        iv4 a0, a1, a2, a3, a4, a5, a6, a7;
        int bad, tries = 0;
        union fr { iv4 v; u64 q[2]; short8 s; };
        fr F[8];
        do {
          asm volatile(
              "global_load_dwordx4 %0, %8, off sc0\n\t"
              "global_load_dwordx4 %1, %8, off offset:1024 sc0\n\t"
              "global_load_dwordx4 %2, %8, off offset:2048 sc0\n\t"
              "global_load_dwordx4 %3, %8, off offset:3072 sc0\n\t"
              "global_load_dwordx4 %4, %9, off sc0\n\t"
              "global_load_dwordx4 %5, %9, off offset:1024 sc0\n\t"
              "global_load_dwordx4 %6, %9, off offset:2048 sc0\n\t"
              "global_load_dwordx4 %7, %9, off offset:3072 sc0\n\t"
              "s_waitcnt vmcnt(0)"
              : "=&v"(a0), "=&v"(a1), "=&v"(a2), "=&v"(a3),
                "=&v"(a4), "=&v"(a5), "=&v"(a6), "=&v"(a7)
              : "v"(p0), "v"(p1)
              : "memory");
          F[0].v = a0; F[1].v = a1; F[2].v = a2; F[3].v = a3;
          F[4].v = a4; F[5].v = a5; F[6].v = a6; F[7].v = a7;
          int mybad = 0;
#pragma unroll
          for (int f = 0; f < 8; ++f)
            mybad |= (F[f].q[0] == POISON) | (F[f].q[1] == POISON);
          bad = __any(mybad);
        } while (bad && ++tries < 64);
        if (bad) {
          atomic_fetch_frags(hq, fi0 * 128 + (size_t)l * 2, af);
        } else {
#pragma unroll
          for (int f = 0; f < 8; ++f) af[f] = F[f].s;
        }
      } else {
        atomic_fetch_frags(hq, fi0 * 128 + (size_t)l * 2, af);
      }
#pragma unroll
      for (int f = 0; f < 8; ++f)
#pragma unroll
        for (int nt = 0; nt < 4; ++nt)
          acc[nt] = __builtin_amdgcn_mfma_f32_16x16x32_bf16(af[f], wf[f][nt], acc[nt], 0, 0, 0);
    }

    const int bi = t & 1;
    f32x4 own = acc[0];
#pragma unroll
    for (int nt = 0; nt < 4; ++nt) {
      if (nt == wv) own = acc[nt];
      else red[bi][wv][nt][l] = acc[nt];
    }
    __syncthreads();  // the only barrier per step (red double-buffered)

    f32x4 tot = own;
#pragma unroll
    for (int p = 0; p < 4; ++p)
      if (p != wv) tot += red[bi][p][wv][l];

    // epilogue: + xp, tanh, C->A transpose via per-wave LDS tile (same-wave
    // write->read, lgkmcnt only), then this wave stores its half-fragment.
    short* lw = &ldsw[wv][0];
#pragma unroll
    for (int i2 = 0; i2 < 4; ++i2) {
      float v = tot[i2] + bf2f(xps[i2]);
      lw[(lq * 4 + i2) * 24 + lr] = f2bf(fast_tanh(v));
    }
    const int kt = 2 * j + (wv >> 1);
    if (l < 32) {
      short8 hv = *(const short8*)&lw[(l & 15) * 24 + (l >> 4) * 8];
      union { short8 s; u64 qq[2]; iv4 v; } u;
      u.s = hv;
      size_t wb = ((size_t)(t * 4 + g) * 32 + kt) * 1024 +
                  (size_t)(l + 32 * (wv & 1)) * 16;
      char* wp = (char*)hbuf + wb;
      if (fast) *(iv4*)wp = u.v;  // plain store -> shared XCD L2 (fast detect)
      // LLC backup (always): rescues bounded-retry trips and the fallback
      __hip_atomic_store((u64*)wp, u.qq[0],
                         __ATOMIC_RELAXED, __HIP_MEMORY_SCOPE_AGENT);
      __hip_atomic_store((u64*)wp + 1, u.qq[1],
                         __ATOMIC_RELAXED, __HIP_MEMORY_SCOPE_AGENT);
    }
  }
}

// ---------------------------------------------------------------------------
// Phase C: out = H @ W_out + b_o.  grid 1024.  (Kernel-boundary L2
// writeback makes the scan's fast-path stores visible here.)
// ---------------------------------------------------------------------------
__global__ __launch_bounds__(256, 1) void outproj_kernel(
    const short* __restrict__ hbuf, const float* __restrict__ w_o,
    const float* __restrict__ o_b, float* __restrict__ out) {
  const int blk = blockIdx.x;
  const int c = blk & 3, s = blk >> 2;
  const int tid = threadIdx.x;
  const int wv = tid >> 6, l = tid & 63, lr = l & 15, lq = l >> 4;

  __shared__ f32x4 red[4][4][64];

  short8 wf[8][4];
#pragma unroll
  for (int f = 0; f < 8; ++f)
#pragma unroll
    for (int nt = 0; nt < 4; ++nt) {
      int o = c * 64 + nt * 16 + lr;
      int k0 = wv * 256 + f * 32 + lq * 8;
      short8 v;
#pragma unroll
      for (int e = 0; e < 8; ++e) v[e] = f2bf(w_o[(size_t)(k0 + e) * 256 + o]);
      wf[f][nt] = v;
    }
  float bias = o_b[c * 64 + wv * 16 + lr];
  const short8* hfr = (const short8*)hbuf;

  for (int it = 0; it < 8; ++it) {
    int m = s + 256 * it;
    int t = m >> 2, g = m & 3;
    short8 af[8];
    size_t base = ((size_t)(t * 4 + g) * 32 + wv * 8) * 64 + l;
#pragma unroll
    for (int f = 0; f < 8; ++f) af[f] = hfr[base + (size_t)f * 64];
    f32x4 acc[4];
#pragma unroll
    for (int nt = 0; nt < 4; ++nt) acc[nt] = (f32x4){0.f, 0.f, 0.f, 0.f};
#pragma unroll
    for (int f = 0; f < 8; ++f)
#pragma unroll
      for (int nt = 0; nt < 4; ++nt)
        acc[nt] = __builtin_amdgcn_mfma_f32_16x16x32_bf16(af[f], wf[f][nt], acc[nt], 0, 0, 0);

    red[wv][0][l] = acc[0];
    red[wv][1][l] = acc[1];
    red[wv][2][l] = acc[2];
    red[wv][3][l] = acc[3];
    __syncthreads();
    f32x4 tot = red[0][wv][l] + red[1][wv][l] + red[2][wv][l] + red[3][wv][l];
#pragma unroll
    for (int i2 = 0; i2 < 4; ++i2) {
      int b = g * 16 + lq * 4 + i2;
      out[((size_t)b * TT + t) * 256 + c * 64 + wv * 16 + lr] = tot[i2] + bias;
    }
    __syncthreads();
  }
}

// ---------------------------------------------------------------------------
extern "C" void kernel_launch(void* const* d_in, const int* in_sizes, int n_in,
                              void* d_out, int out_size, void* d_ws, size_t ws_size,
                              hipStream_t stream) {
  const float* inp  = (const float*)d_in[0];
  const float* w_in = (const float*)d_in[1];
  const float* w_h  = (const float*)d_in[2];
  const float* h_b  = (const float*)d_in[3];
  const float* w_o  = (const float*)d_in[4];
  const float* o_b  = (const float*)d_in[5];

  // workspace (harness poisons to 0xAA before every launch — both the
  // data-as-flag protocol and the xcmap check depend on that)
  short* xp    = (short*)d_ws;                              // 64 MiB (bf16)
  short* hbuf  = (short*)((char*)d_ws + (size_t)67108864);  // 64 MiB
  int*   xcmap = (int*)((char*)d_ws + (size_t)134217728);   // 256 B

  xproj_kernel<<<1024, 256, 0, stream>>>(inp, w_in, h_b, xp);
  scan_kernel<<<128, 256, 0, stream>>>(xp, w_h, hbuf, xcmap);
  outproj_kernel<<<1024, 256, 0, stream>>>(hbuf, w_o, o_b, (float*)d_out);
}

// Round 8
// 1615.460 us; speedup vs baseline: 5.5736x; 5.5736x over previous
//
#include <hip/hip_runtime.h>
#include <stdint.h>
#include <stddef.h>

// SimpleRNN: B=64, T=512, D_IN=256, H=1024, D_OUT=256 (all fp32 in/out)
//
//  A) xproj:  xp = inputs @ W_in + b_h, bf16, pre-swizzled in MFMA C-frag
//     order so the scan adds it with one 8B load.
//  B) scan:   persistent, 4 groups(16 batch rows) x 16 WGs.  WG j of group
//     g owns h cols [64j,64j+64); W_h[:,cols] register resident as bf16
//     B-fragments.  Exchange (round 8):
//       - grid 128, group g = blk%8 (live iff <4): round-robin block->XCD
//         mapping puts all 16 WGs of a group on ONE XCD -> shared L2
//         (verified at runtime via HW_REG_XCC_ID; else LLC fallback).
//       - producer h stores: inline-asm global_store_dwordx4 (DSE-proof —
//         R7's plain store was dead-store-eliminated by the covering
//         atomic stores, which is why every sc0 poll failed) -> lands in
//         the shared XCD L2.  PLUS atomic backup stores to a SEPARATE
//         LLC buffer (fallback path + bounded-retry rescue).
//       - consumer: bounded (6) sc0 dwordx4 poll rounds on the L2 buffer;
//         on failure or fast==false, R3's merged detect+fetch via LLC
//         relaxed atomics on the backup buffer.
//       - data-as-flag: d_ws poisoned 0xAA by the harness; fragment ready
//         when no qword == 0xAAAA..AA.
//  C) outproj: out = H @ W_out + b_o, A-frags from the primary h buffer
//     (kernel-boundary writeback makes asm stores visible).

#define TT 512
#define HH 1024

typedef __attribute__((ext_vector_type(8))) short short8;
typedef __attribute__((ext_vector_type(4))) short s16x4;
typedef __attribute__((ext_vector_type(4))) float f32x4;
typedef __attribute__((ext_vector_type(4))) int iv4;
typedef unsigned long long u64;

#define POISON 0xAAAAAAAAAAAAAAAAull

__device__ inline short f2bf(float f) {
  uint32_t u = __builtin_bit_cast(uint32_t, f);
  u += 0x7fffu + ((u >> 16) & 1u);
  return (short)(u >> 16);
}

__device__ inline float bf2f(short s) {
  uint32_t u = ((uint32_t)(uint16_t)s) << 16;
  return __builtin_bit_cast(float, u);
}

__device__ inline float fast_tanh(float x) {
  float ax = fabsf(x);
  float e = __expf(-2.f * ax);
  float r = (1.f - e) * __builtin_amdgcn_rcpf(1.f + e);
  return copysignf(r, x);
}

// LLC-atomic fetch of 8 fragments (16 qwords), retry until poison-free.
__device__ inline void atomic_fetch_frags(const u64* hq, size_t base, short8* af) {
  u64 q[16];
  int bad;
  do {
#pragma unroll
    for (int f = 0; f < 8; ++f) {
      q[2 * f]     = __hip_atomic_load(hq + base + (size_t)f * 128,
                                       __ATOMIC_RELAXED, __HIP_MEMORY_SCOPE_AGENT);
      q[2 * f + 1] = __hip_atomic_load(hq + base + (size_t)f * 128 + 1,
                                       __ATOMIC_RELAXED, __HIP_MEMORY_SCOPE_AGENT);
    }
    int mybad = 0;
#pragma unroll
    for (int i = 0; i < 16; ++i) mybad |= (q[i] == POISON);
    bad = __any(mybad);
  } while (bad);
#pragma unroll
  for (int f = 0; f < 8; ++f) {
    union { u64 qq[2]; short8 s; } u;
    u.qq[0] = q[2 * f];
    u.qq[1] = q[2 * f + 1];
    af[f] = u.s;
  }
}

// ---------------------------------------------------------------------------
// Phase A: xp[(t*4+g)*64 + ntile][lane][4] = inputs @ W_in + b_h  (bf16)
// ---------------------------------------------------------------------------
__global__ __launch_bounds__(256, 1) void xproj_kernel(
    const float* __restrict__ inp, const float* __restrict__ w_in,
    const float* __restrict__ h_b, short* __restrict__ xp) {
  const int blk = blockIdx.x;
  const int c = blk & 3, s = blk >> 2;
  const int tid = threadIdx.x;
  const int wv = tid >> 6, l = tid & 63, lr = l & 15, lq = l >> 4;

  __shared__ short ldsA[16 * 264];

  short8 wf[8][4];
#pragma unroll
  for (int kt = 0; kt < 8; ++kt)
#pragma unroll
    for (int nt = 0; nt < 4; ++nt) {
      int col = c * 256 + (wv * 4 + nt) * 16 + lr;
      int k0 = kt * 32 + lq * 8;
      short8 v;
#pragma unroll
      for (int e = 0; e < 8; ++e) v[e] = f2bf(w_in[(size_t)(k0 + e) * HH + col]);
      wf[kt][nt] = v;
    }
  float bias[4];
#pragma unroll
  for (int nt = 0; nt < 4; ++nt) bias[nt] = h_b[c * 256 + (wv * 4 + nt) * 16 + lr];

  for (int it = 0; it < 8; ++it) {
    int m = s + 256 * it;
    int t = m >> 2, g = m & 3;
    {
      int row = tid >> 4, cb = (tid & 15) * 16;
      const float* src = inp + ((size_t)(g * 16 + row) * TT + t) * 256 + cb;
      f32x4 v0 = *(const f32x4*)(src);
      f32x4 v1 = *(const f32x4*)(src + 4);
      f32x4 v2 = *(const f32x4*)(src + 8);
      f32x4 v3 = *(const f32x4*)(src + 12);
      short8 sa, sb;
      sa[0]=f2bf(v0[0]); sa[1]=f2bf(v0[1]); sa[2]=f2bf(v0[2]); sa[3]=f2bf(v0[3]);
      sa[4]=f2bf(v1[0]); sa[5]=f2bf(v1[1]); sa[6]=f2bf(v1[2]); sa[7]=f2bf(v1[3]);
      sb[0]=f2bf(v2[0]); sb[1]=f2bf(v2[1]); sb[2]=f2bf(v2[2]); sb[3]=f2bf(v2[3]);
      sb[4]=f2bf(v3[0]); sb[5]=f2bf(v3[1]); sb[6]=f2bf(v3[2]); sb[7]=f2bf(v3[3]);
      *(short8*)&ldsA[row * 264 + cb] = sa;
      *(short8*)&ldsA[row * 264 + cb + 8] = sb;
    }
    __syncthreads();

    f32x4 acc[4];
#pragma unroll
    for (int nt = 0; nt < 4; ++nt) acc[nt] = (f32x4){0.f, 0.f, 0.f, 0.f};
#pragma unroll
    for (int kt = 0; kt < 8; ++kt) {
      short8 a = *(const short8*)&ldsA[lr * 264 + kt * 32 + lq * 8];
#pragma unroll
      for (int nt = 0; nt < 4; ++nt)
        acc[nt] = __builtin_amdgcn_mfma_f32_16x16x32_bf16(a, wf[kt][nt], acc[nt], 0, 0, 0);
    }
#pragma unroll
    for (int nt = 0; nt < 4; ++nt) {
      s16x4 o;
#pragma unroll
      for (int i2 = 0; i2 < 4; ++i2) o[i2] = f2bf(acc[nt][i2] + bias[nt]);
      *(s16x4*)(xp + ((size_t)(t * 4 + g) * 64 + c * 16 + wv * 4 + nt) * 256 + l * 4) = o;
    }
    __syncthreads();
  }
}

// ---------------------------------------------------------------------------
// Phase B: persistent scan.  grid 128: r=blk&7, j=blk>>3; live iff r<4
// (g=r).  hbuf frag fi=(t*4+g)*32+kt: 64 lanes x 16B, A-frag layout.
// hback: identical layout, written via LLC atomics (backup/fallback).
// ---------------------------------------------------------------------------
__global__ __launch_bounds__(256, 1) void scan_kernel(
    const short* __restrict__ xp, const float* __restrict__ w_h,
    short* __restrict__ hbuf, short* __restrict__ hback,
    int* __restrict__ xcmap) {
  const int blk = blockIdx.x;
  const int r = blk & 7, j = blk >> 3;
  if (r >= 4) return;
  const int g = r;
  const int tid = threadIdx.x;
  const int wv = tid >> 6, l = tid & 63, lr = l & 15, lq = l >> 4;
  const int ntg = j * 4 + wv;

  __shared__ f32x4 red[2][4][4][64];  // [t&1][src wave][n-tile][lane]
  __shared__ short ldsw[4][16 * 24];  // per-wave C->A transpose tile

  // --- XCD co-residency check (once) -------------------------------------
  int myxcc = __builtin_amdgcn_s_getreg((31 << 11) | 20) & 0xf;  // HW_REG_XCC_ID
  if (tid == 0)
    __hip_atomic_store(xcmap + g * 16 + j, myxcc,
                       __ATOMIC_RELAXED, __HIP_MEMORY_SCOPE_AGENT);
  int e;
  do {
    e = __hip_atomic_load(xcmap + g * 16 + (l & 15),
                          __ATOMIC_RELAXED, __HIP_MEMORY_SCOPE_AGENT);
  } while (__any(e < 0 || e > 15));
  const int e0 = __shfl(e, 0);
  const bool fast = !__any(e != e0);   // wave-uniform, same for all waves

  // --- W_h B-fragments, register resident --------------------------------
  short8 wf[8][4];
#pragma unroll
  for (int f = 0; f < 8; ++f)
#pragma unroll
    for (int nt = 0; nt < 4; ++nt) {
      int n = j * 64 + nt * 16 + lr;
      int k0 = wv * 256 + f * 32 + lq * 8;
      short8 v;
#pragma unroll
      for (int e2 = 0; e2 < 8; ++e2) v[e2] = f2bf(w_h[(size_t)(k0 + e2) * HH + n]);
      wf[f][nt] = v;
    }

  const u64* hqb = (const u64*)hback;

  for (int t = 0; t < TT; ++t) {
    s16x4 xps = *(const s16x4*)(xp + ((size_t)(t * 4 + g) * 64 + ntg) * 256 + l * 4);

    f32x4 acc[4];
#pragma unroll
    for (int nt = 0; nt < 4; ++nt) acc[nt] = (f32x4){0.f, 0.f, 0.f, 0.f};

    if (t > 0) {
      short8 af[8];
      const size_t fi0 = ((size_t)(t - 1) * 4 + g) * 32 + wv * 8;
      bool need_fb = true;
      if (fast) {
        // sc0 loads bypass L1, served by the shared XCD L2 where the
        // producers' asm stores landed.  Bounded retry; LLC backup
        // guarantees the fallback succeeds if this trips.
        uint64_t p0 = (uint64_t)((const char*)hbuf + fi0 * 1024 + (size_t)l * 16);
        uint64_t p1 = p0 + 4096;
        iv4 a0, a1, a2, a3, a4, a5, a6, a7;
        int bad, tries = 0;
        union fr { iv4 v; u64 q[2]; short8 s; };
        fr F[8];
        do {
          asm volatile(
              "global_load_dwordx4 %0, %8, off sc0\n\t"
              "global_load_dwordx4 %1, %8, off offset:1024 sc0\n\t"
              "global_load_dwordx4 %2, %8, off offset:2048 sc0\n\t"
              "global_load_dwordx4 %3, %8, off offset:3072 sc0\n\t"
              "global_load_dwordx4 %4, %9, off sc0\n\t"
              "global_load_dwordx4 %5, %9, off offset:1024 sc0\n\t"
              "global_load_dwordx4 %6, %9, off offset:2048 sc0\n\t"
              "global_load_dwordx4 %7, %9, off offset:3072 sc0\n\t"
              "s_waitcnt vmcnt(0)"
              : "=&v"(a0), "=&v"(a1), "=&v"(a2), "=&v"(a3),
                "=&v"(a4), "=&v"(a5), "=&v"(a6), "=&v"(a7)
              : "v"(p0), "v"(p1)
              : "memory");
          F[0].v = a0; F[1].v = a1; F[2].v = a2; F[3].v = a3;
          F[4].v = a4; F[5].v = a5; F[6].v = a6; F[7].v = a7;
          int mybad = 0;
#pragma unroll
          for (int f = 0; f < 8; ++f)
            mybad |= (F[f].q[0] == POISON) | (F[f].q[1] == POISON);
          bad = __any(mybad);
        } while (bad && ++tries < 6);
        if (!bad) {
#pragma unroll
          for (int f = 0; f < 8; ++f) af[f] = F[f].s;
          need_fb = false;
        }
      }
      if (need_fb)
        atomic_fetch_frags(hqb, fi0 * 128 + (size_t)l * 2, af);
#pragma unroll
      for (int f = 0; f < 8; ++f)
#pragma unroll
        for (int nt = 0; nt < 4; ++nt)
          acc[nt] = __builtin_amdgcn_mfma_f32_16x16x32_bf16(af[f], wf[f][nt], acc[nt], 0, 0, 0);
    }

    const int bi = t & 1;
    f32x4 own = acc[0];
#pragma unroll
    for (int nt = 0; nt < 4; ++nt) {
      if (nt == wv) own = acc[nt];
      else red[bi][wv][nt][l] = acc[nt];
    }
    __syncthreads();  // the only barrier per step (red double-buffered)

    f32x4 tot = own;
#pragma unroll
    for (int p = 0; p < 4; ++p)
      if (p != wv) tot += red[bi][p][wv][l];

    // epilogue: + xp, tanh, C->A transpose via per-wave LDS tile (same-wave
    // write->read, lgkmcnt only), then this wave stores its half-fragment.
    short* lw = &ldsw[wv][0];
#pragma unroll
    for (int i2 = 0; i2 < 4; ++i2) {
      float v = tot[i2] + bf2f(xps[i2]);
      lw[(lq * 4 + i2) * 24 + lr] = f2bf(fast_tanh(v));
    }
    const int kt = 2 * j + (wv >> 1);
    if (l < 32) {
      short8 hv = *(const short8*)&lw[(l & 15) * 24 + (l >> 4) * 8];
      union { short8 s; u64 qq[2]; iv4 v; } u;
      u.s = hv;
      size_t wb = ((size_t)(t * 4 + g) * 32 + kt) * 1024 +
                  (size_t)(l + 32 * (wv & 1)) * 16;
      // primary: DSE-proof asm store -> shared XCD L2 (fast-path source)
      uint64_t wp = (uint64_t)((char*)hbuf + wb);
      asm volatile("global_store_dwordx4 %0, %1, off"
                   :: "v"(wp), "v"(u.v) : "memory");
      // backup: LLC atomics to the SEPARATE backup buffer (fallback source)
      u64* bp = (u64*)((char*)hback + wb);
      __hip_atomic_store(bp, u.qq[0],
                         __ATOMIC_RELAXED, __HIP_MEMORY_SCOPE_AGENT);
      __hip_atomic_store(bp + 1, u.qq[1],
                         __ATOMIC_RELAXED, __HIP_MEMORY_SCOPE_AGENT);
    }
  }
}

// ---------------------------------------------------------------------------
// Phase C: out = H @ W_out + b_o.  grid 1024.  Reads the primary hbuf
// (asm stores are written back at the scan kernel's dispatch-end).
// ---------------------------------------------------------------------------
__global__ __launch_bounds__(256, 1) void outproj_kernel(
    const short* __restrict__ hbuf, const float* __restrict__ w_o,
    const float* __restrict__ o_b, float* __restrict__ out) {
  const int blk = blockIdx.x;
  const int c = blk & 3, s = blk >> 2;
  const int tid = threadIdx.x;
  const int wv = tid >> 6, l = tid & 63, lr = l & 15, lq = l >> 4;

  __shared__ f32x4 red[4][4][64];

  short8 wf[8][4];
#pragma unroll
  for (int f = 0; f < 8; ++f)
#pragma unroll
    for (int nt = 0; nt < 4; ++nt) {
      int o = c * 64 + nt * 16 + lr;
      int k0 = wv * 256 + f * 32 + lq * 8;
      short8 v;
#pragma unroll
      for (int e = 0; e < 8; ++e) v[e] = f2bf(w_o[(size_t)(k0 + e) * 256 + o]);
      wf[f][nt] = v;
    }
  float bias = o_b[c * 64 + wv * 16 + lr];
  const short8* hfr = (const short8*)hbuf;

  for (int it = 0; it < 8; ++it) {
    int m = s + 256 * it;
    int t = m >> 2, g = m & 3;
    short8 af[8];
    size_t base = ((size_t)(t * 4 + g) * 32 + wv * 8) * 64 + l;
#pragma unroll
    for (int f = 0; f < 8; ++f) af[f] = hfr[base + (size_t)f * 64];
    f32x4 acc[4];
#pragma unroll
    for (int nt = 0; nt < 4; ++nt) acc[nt] = (f32x4){0.f, 0.f, 0.f, 0.f};
#pragma unroll
    for (int f = 0; f < 8; ++f)
#pragma unroll
      for (int nt = 0; nt < 4; ++nt)
        acc[nt] = __builtin_amdgcn_mfma_f32_16x16x32_bf16(af[f], wf[f][nt], acc[nt], 0, 0, 0);

    red[wv][0][l] = acc[0];
    red[wv][1][l] = acc[1];
    red[wv][2][l] = acc[2];
    red[wv][3][l] = acc[3];
    __syncthreads();
    f32x4 tot = red[0][wv][l] + red[1][wv][l] + red[2][wv][l] + red[3][wv][l];
#pragma unroll
    for (int i2 = 0; i2 < 4; ++i2) {
      int b = g * 16 + lq * 4 + i2;
      out[((size_t)b * TT + t) * 256 + c * 64 + wv * 16 + lr] = tot[i2] + bias;
    }
    __syncthreads();
  }
}

// ---------------------------------------------------------------------------
extern "C" void kernel_launch(void* const* d_in, const int* in_sizes, int n_in,
                              void* d_out, int out_size, void* d_ws, size_t ws_size,
                              hipStream_t stream) {
  const float* inp  = (const float*)d_in[0];
  const float* w_in = (const float*)d_in[1];
  const float* w_h  = (const float*)d_in[2];
  const float* h_b  = (const float*)d_in[3];
  const float* w_o  = (const float*)d_in[4];
  const float* o_b  = (const float*)d_in[5];

  // workspace (harness poisons to 0xAA before every launch — the
  // data-as-flag protocol and the xcmap check depend on that)
  short* xp    = (short*)d_ws;                               // 64 MiB (bf16)
  short* hbuf  = (short*)((char*)d_ws + (size_t)67108864);   // 64 MiB (L2 path)
  short* hback = (short*)((char*)d_ws + (size_t)134217728);  // 64 MiB (LLC path)
  int*   xcmap = (int*)((char*)d_ws + (size_t)201326592);    // 256 B

  xproj_kernel<<<1024, 256, 0, stream>>>(inp, w_in, h_b, xp);
  scan_kernel<<<128, 256, 0, stream>>>(xp, w_h, hbuf, hback, xcmap);
  outproj_kernel<<<1024, 256, 0, stream>>>(hbuf, w_o, o_b, (float*)d_out);
}